// Round 2
// baseline (673.691 us; speedup 1.0000x reference)
//
#include <hip/hip_runtime.h>

#define BDIM 8
#define CDIM 256
#define HDIM 96
#define WDIM 96
#define GRP  4
#define CG   64          // channels per group
#define SH   192         // s*H
#define SW   192         // s*W
#define HW   (HDIM*WDIM) // 9216

// ---------------------------------------------------------------------------
// Kernel 1: per-pixel 256->32 dot product (1x1 conv offset head).
// w_off staged in LDS TRANSPOSED (wlds[c*32+o]) so the per-c inner loop is
// 8 uniform ds_read_b128 (broadcast, conflict-free) + 32 FMAs. 64-thread
// blocks -> 1152 blocks (4.5 blocks/CU) for load balance. Writes offsets
// pre-scaled by 0.25 into ws, layout [B][32][H][W].
// ---------------------------------------------------------------------------
__global__ __launch_bounds__(64) void dysample_offset_kernel(
    const float* __restrict__ x,
    const float* __restrict__ w_off,
    const float* __restrict__ b_off,
    float* __restrict__ off)
{
    __shared__ float wlds[CDIM * 32];   // 32 KB, [c][o]

    // Cooperative transpose load: lane o = tid&31 owns output column o.
    // LDS writes: lanes 0..31 hit banks 0..31 (bank = (c*32+o)%32 = o),
    // second half-wave aliases 2-way (free).
    {
        int o    = threadIdx.x & 31;
        int half = threadIdx.x >> 5;          // 0..1
        const float* wrow = w_off + o * CDIM; // w_off[o][*], L1/L2-hot (32 KB total)
        #pragma unroll 4
        for (int k = 0; k < 128; ++k) {
            int c = half * 128 + k;
            wlds[c * 32 + o] = wrow[c];
        }
    }
    __syncthreads();

    // 144 blocks per batch image (9216/64): a block never straddles b.
    int b  = blockIdx.x / 144;
    int hw = (blockIdx.x - b * 144) * 64 + threadIdx.x;

    float acc[32];
    #pragma unroll
    for (int o = 0; o < 32; ++o) acc[o] = b_off[o];

    const float* xp = x + (size_t)b * CDIM * HW + hw;
    #pragma unroll 2
    for (int c = 0; c < CDIM; ++c) {
        float xv = xp[(size_t)c * HW];        // coalesced 256B across the wave
        const float* wr = &wlds[c * 32];      // 128B-aligned -> ds_read_b128 x8
        #pragma unroll
        for (int o = 0; o < 32; ++o)
            acc[o] = fmaf(xv, wr[o], acc[o]);
    }

    float* op = off + (size_t)b * 32 * HW + hw;
    #pragma unroll
    for (int o = 0; o < 32; ++o)
        op[(size_t)o * HW] = acc[o] * 0.25f;
}

// ---------------------------------------------------------------------------
// Kernel 2: bilinear sampling. Block = (row-tile of 8, gi, b); 192 threads =
// output columns. Bilinear params for all 8 rows precomputed into registers;
// channel loop OUTER so each (ch, input-row) stays L1-hot across the 8 rows
// (~8 reuses per cache line inside the block instead of cross-block misses).
// ---------------------------------------------------------------------------
__global__ __launch_bounds__(192) void dysample_sample_kernel(
    const float* __restrict__ x,
    const float* __restrict__ off,
    float* __restrict__ out)
{
    int cc = threadIdx.x;     // 0..191 output column
    int rt = blockIdx.x;      // 0..23  row tile (8 rows each)
    int gi = blockIdx.y;      // 0..3
    int b  = blockIdx.z;      // 0..7

    int w  = cc >> 1, s2 = cc & 1;

    int   i00[8], i01[8], i10[8], i11[8];
    float w00[8], w01[8], w10[8], w11[8];

    #pragma unroll
    for (int j = 0; j < 8; ++j) {
        int r   = rt * 8 + j;
        int h   = r >> 1, s1 = r & 1;
        int o16 = gi * 4 + s1 * 2 + s2;

        size_t obase = ((size_t)b * 32 + o16) * HW + (size_t)h * WDIM + w;
        float ox = off[obase];
        float oy = off[obase + (size_t)16 * HW];

        float ix = fminf(fmaxf((float)w + ox, 0.0f), (float)(WDIM - 1));
        float iy = fminf(fmaxf((float)h + oy, 0.0f), (float)(HDIM - 1));
        float x0f = floorf(ix), y0f = floorf(iy);
        float wx = ix - x0f,   wy = iy - y0f;
        int x0 = (int)x0f, y0 = (int)y0f;
        int x1 = min(x0 + 1, WDIM - 1);
        int y1 = min(y0 + 1, HDIM - 1);

        w00[j] = (1.0f - wy) * (1.0f - wx);
        w01[j] = (1.0f - wy) * wx;
        w10[j] = wy * (1.0f - wx);
        w11[j] = wy * wx;
        i00[j] = y0 * WDIM + x0;  i01[j] = y0 * WDIM + x1;
        i10[j] = y1 * WDIM + x0;  i11[j] = y1 * WDIM + x1;
    }

    const float* xp = x   + ((size_t)b * CDIM + (size_t)gi * CG) * HW;
    float*       op = out + (((size_t)b * CDIM + (size_t)gi * CG) * SH
                             + (size_t)rt * 8) * SW + cc;

    for (int ch = 0; ch < CG; ++ch) {
        const float* p  = xp + (size_t)ch * HW;
        float*       o2 = op + (size_t)ch * (SH * SW);
        #pragma unroll
        for (int j = 0; j < 8; ++j) {
            float v = p[i00[j]] * w00[j] + p[i01[j]] * w01[j]
                    + p[i10[j]] * w10[j] + p[i11[j]] * w11[j];
            o2[(size_t)j * SW] = v;   // coalesced 768B row store
        }
    }
}

extern "C" void kernel_launch(void* const* d_in, const int* in_sizes, int n_in,
                              void* d_out, int out_size, void* d_ws, size_t ws_size,
                              hipStream_t stream)
{
    const float* x     = (const float*)d_in[0];
    const float* w_off = (const float*)d_in[1];
    const float* b_off = (const float*)d_in[2];
    float* out = (float*)d_out;
    float* off = (float*)d_ws;   // 8*32*96*96*4 = 9.44 MB scratch

    // Kernel 1: 8 batches * 144 blocks of 64 threads
    dysample_offset_kernel<<<BDIM * (HW / 64), 64, 0, stream>>>(x, w_off, b_off, off);

    // Kernel 2: grid (24 row-tiles, 4 groups, 8 batch), 192 threads = columns
    dysample_sample_kernel<<<dim3(SH / 8, GRP, BDIM), 192, 0, stream>>>(x, off, out);
}